// Round 1
// baseline (150.603 us; speedup 1.0000x reference)
//
#include <hip/hip_runtime.h>

// Problem constants (fixed by reference setup_inputs)
#define N_TOTAL 8388608
#define SEG 64
#define NSEG (N_TOTAL / SEG)      // 131072 segments
#define TPB 256
#define BLOCKS 2048
#define WAVES_TOTAL (BLOCKS * TPB / 64)   // 8192 waves, 32/CU

// One wave (64 lanes) processes one 64-element segment entirely in-register:
//   1. key = (t<<6)|(63-lane): descending bitonic sort by t, stable ties
//      (matches jnp.argsort(-t) which is stable: equal t -> smaller idx first)
//   2. gather z = exp(m + v/2) into sorted order (single bpermute)
//   3. suffix-sum of z across lanes (Hillis-Steele via shfl_down)
//   4. Sum_j logS_j = Sum_j(-m_j + v_j/2)  [permutation-invariant, pre-sort]
//                   + Sum_j log(suffix_j)
__global__ __launch_bounds__(TPB) void mledis_seg_kernel(
    const float* __restrict__ mean,
    const float* __restrict__ variance,
    const int*   __restrict__ targets,
    float* __restrict__ partial)
{
    const int lane = threadIdx.x & 63;
    const int waveInBlock = threadIdx.x >> 6;
    const int waveId = blockIdx.x * (TPB / 64) + waveInBlock;

    float waveSum = 0.0f;

    for (int seg = waveId; seg < NSEG; seg += WAVES_TOTAL) {
        const int idx = (seg << 6) + lane;
        const float m = mean[idx];
        const float v = variance[idx];
        const unsigned t = (unsigned)targets[idx];   // values in [0, 1e6) < 2^20

        const float z = __expf(m + 0.5f * v);
        const float invar = 0.5f * v - m;            // order-invariant part of logS

        // ---- descending bitonic sort of keys across the wave ----
        unsigned key = (t << 6) | (63u - (unsigned)lane);
        #pragma unroll
        for (int k = 2; k <= 64; k <<= 1) {
            #pragma unroll
            for (int j = k >> 1; j > 0; j >>= 1) {
                unsigned other = __shfl_xor(key, j, 64);
                bool lower = (lane & j) == 0;
                bool ascb  = (lane & k) == 0;
                unsigned mn = key < other ? key : other;
                unsigned mx = key < other ? other : key;
                // inverted comparator -> overall DESCENDING sort
                key = (ascb == lower) ? mx : mn;
            }
        }
        const int orig = 63 - (int)(key & 63u);      // original lane of sorted pos

        // gather z into sorted order
        const float zs = __shfl(z, orig, 64);

        // ---- inclusive suffix sum: s[j] = sum_{i>=j} zs[i] ----
        float s = zs;
        #pragma unroll
        for (int off = 1; off < 64; off <<= 1) {
            float o = __shfl_down(s, off, 64);
            if (lane + off < 64) s += o;
        }

        waveSum += invar + __logf(s);
    }

    // ---- wave reduction ----
    #pragma unroll
    for (int off = 32; off > 0; off >>= 1)
        waveSum += __shfl_xor(waveSum, off, 64);

    __shared__ float acc[TPB / 64];
    if (lane == 0) acc[waveInBlock] = waveSum;
    __syncthreads();
    if (threadIdx.x == 0) {
        float b = 0.0f;
        #pragma unroll
        for (int i = 0; i < TPB / 64; ++i) b += acc[i];
        partial[blockIdx.x] = b;
    }
}

__global__ __launch_bounds__(TPB) void mledis_final_reduce(
    const float* __restrict__ partial, float* __restrict__ out)
{
    float s = 0.0f;
    for (int i = threadIdx.x; i < BLOCKS; i += TPB) s += partial[i];
    #pragma unroll
    for (int off = 32; off > 0; off >>= 1) s += __shfl_xor(s, off, 64);

    __shared__ float acc[TPB / 64];
    const int lane = threadIdx.x & 63;
    const int w = threadIdx.x >> 6;
    if (lane == 0) acc[w] = s;
    __syncthreads();
    if (threadIdx.x == 0) {
        float tot = 0.0f;
        #pragma unroll
        for (int i = 0; i < TPB / 64; ++i) tot += acc[i];
        // mean over SEG then /b  ==  total / N
        out[0] = tot * (1.0f / (float)N_TOTAL);
    }
}

extern "C" void kernel_launch(void* const* d_in, const int* in_sizes, int n_in,
                              void* d_out, int out_size, void* d_ws, size_t ws_size,
                              hipStream_t stream) {
    const float* mean     = (const float*)d_in[0];
    const float* variance = (const float*)d_in[1];
    const int*   targets  = (const int*)d_in[2];   // harness passes integers as int32
    // d_in[3] is scope (==64), baked into SEG

    float* partial = (float*)d_ws;                 // BLOCKS floats = 8 KB
    float* out = (float*)d_out;

    mledis_seg_kernel<<<BLOCKS, TPB, 0, stream>>>(mean, variance, targets, partial);
    mledis_final_reduce<<<1, TPB, 0, stream>>>(partial, out);
}

// Round 2
// 131.241 us; speedup vs baseline: 1.1475x; 1.1475x over previous
//
#include <hip/hip_runtime.h>

// Problem constants (fixed by reference setup_inputs)
#define N_TOTAL 8388608
#define SEG 64
#define NSEG (N_TOTAL / SEG)        // 131072 segments
#define NPAIR (NSEG / 2)            // 65536 segment-pairs
#define TPB 256
#define BLOCKS 4096
#define WAVES (BLOCKS * TPB / 64)   // 16384 waves
#define ITERS (NPAIR / WAVES)       // 4 pair-iterations per wave (exact)

// One wave processes TWO 64-element segments per iteration:
//   lanes 0-31 hold segment A, lanes 32-63 hold segment B,
//   each lane holds elements e=2*l5 and e=2*l5+1 of its segment.
// Bitonic sort levels with element-distance 1 are in-register (VALU);
// cross-lane levels shuffle both slots (2 DS ops serving 2 segments).
// Sum_j logS_j = Sum_j(0.5 v_j - m_j)            [order-invariant]
//              + Sum_j log(suffix_j of sorted z)
__global__ __launch_bounds__(TPB) void mledis_seg2(
    const float2* __restrict__ mean2,
    const float2* __restrict__ var2,
    const int2*   __restrict__ tgt2,
    float* __restrict__ partial)
{
    const int lane = threadIdx.x & 63;
    const int h    = lane >> 5;        // which half-wave / which segment of the pair
    const int l5   = lane & 31;        // lane within half
    const int waveId = blockIdx.x * (TPB / 64) + (threadIdx.x >> 6);

    float acc = 0.0f;

    #pragma unroll 2
    for (int it = 0; it < ITERS; ++it) {
        const int pairIdx = waveId + it * WAVES;          // 0..NPAIR-1
        const int base2   = pairIdx * 64 + h * 32 + l5;   // float2 index (32 float2 per segment)

        const float2 m = mean2[base2];
        const float2 v = var2[base2];
        const int2   t = tgt2[base2];

        const float z0 = __expf(fmaf(0.5f, v.x, m.x));
        const float z1 = __expf(fmaf(0.5f, v.y, m.y));
        acc += fmaf(0.5f, v.x, -m.x) + fmaf(0.5f, v.y, -m.y);  // order-invariant part

        // keys: (t<<6) | (63-e)  -> descending sort by t, stable ties (matches argsort(-t))
        const unsigned e0 = 2u * (unsigned)l5;
        unsigned k0 = (((unsigned)t.x) << 6) | (63u - e0);
        unsigned k1 = (((unsigned)t.y) << 6) | (63u - (e0 + 1u));

        // ---- bitonic sort (descending) over 64 elements, 2 per lane ----
        #pragma unroll
        for (int k = 2; k <= 64; k <<= 1) {
            #pragma unroll
            for (int j = k >> 1; j >= 2; j >>= 1) {
                const int d = j >> 1;                       // lane xor distance
                const unsigned o0 = __shfl_xor(k0, d, 64);  // stays within half (d<=16)
                const unsigned o1 = __shfl_xor(k1, d, 64);
                const bool lower = (l5 & d) == 0;           // (e & j)==0
                const bool ascb  = (l5 & (k >> 1)) == 0;    // (e & k)==0
                const bool sel   = (ascb == lower);
                const unsigned mn0 = min(k0, o0), mx0 = max(k0, o0);
                const unsigned mn1 = min(k1, o1), mx1 = max(k1, o1);
                k0 = sel ? mx0 : mn0;
                k1 = sel ? mx1 : mn1;
            }
            {   // j == 1: in-register pair exchange
                const bool ascb = (l5 & (k >> 1)) == 0;     // (e & k)==0
                const unsigned mn = min(k0, k1), mx = max(k0, k1);
                k0 = ascb ? mx : mn;   // slot0 is the "lower" element
                k1 = ascb ? mn : mx;
            }
        }

        // ---- gather z into sorted order (4 bpermutes serve both segments) ----
        const int o0i = 63 - (int)(k0 & 63u);   // original element index of sorted pos e0
        const int o1i = 63 - (int)(k1 & 63u);
        const int a0 = (h * 32 + (o0i >> 1)) << 2;   // byte lane address for bpermute
        const int a1 = (h * 32 + (o1i >> 1)) << 2;
        const int zi0 = __float_as_int(z0);
        const int zi1 = __float_as_int(z1);
        const float g00 = __int_as_float(__builtin_amdgcn_ds_bpermute(a0, zi0));
        const float g01 = __int_as_float(__builtin_amdgcn_ds_bpermute(a0, zi1));
        const float g10 = __int_as_float(__builtin_amdgcn_ds_bpermute(a1, zi0));
        const float g11 = __int_as_float(__builtin_amdgcn_ds_bpermute(a1, zi1));
        const float zs0 = (o0i & 1) ? g01 : g00;
        const float zs1 = (o1i & 1) ? g11 : g10;

        // ---- inclusive suffix sum of pair sums across the 32-lane half ----
        float T = zs0 + zs1;
        #pragma unroll
        for (int off = 1; off < 32; off <<= 1) {
            const float o = __shfl_down(T, off, 32);
            if (l5 + off < 32) T += o;
        }
        // suffix for slot0 element = T; for slot1 element = T - zs0
        acc += __logf(T) + __logf(T - zs0);
    }

    // ---- wave reduction ----
    #pragma unroll
    for (int off = 32; off > 0; off >>= 1)
        acc += __shfl_xor(acc, off, 64);

    __shared__ float sacc[TPB / 64];
    const int waveInBlock = threadIdx.x >> 6;
    if (lane == 0) sacc[waveInBlock] = acc;
    __syncthreads();
    if (threadIdx.x == 0) {
        float b = 0.0f;
        #pragma unroll
        for (int i = 0; i < TPB / 64; ++i) b += sacc[i];
        partial[blockIdx.x] = b;
    }
}

__global__ __launch_bounds__(TPB) void mledis_final_reduce(
    const float* __restrict__ partial, float* __restrict__ out)
{
    float s = 0.0f;
    for (int i = threadIdx.x; i < BLOCKS; i += TPB) s += partial[i];
    #pragma unroll
    for (int off = 32; off > 0; off >>= 1) s += __shfl_xor(s, off, 64);

    __shared__ float sacc[TPB / 64];
    const int lane = threadIdx.x & 63;
    const int w = threadIdx.x >> 6;
    if (lane == 0) sacc[w] = s;
    __syncthreads();
    if (threadIdx.x == 0) {
        float tot = 0.0f;
        #pragma unroll
        for (int i = 0; i < TPB / 64; ++i) tot += sacc[i];
        out[0] = tot * (1.0f / (float)N_TOTAL);   // mean over SEG then / b  ==  / N
    }
}

extern "C" void kernel_launch(void* const* d_in, const int* in_sizes, int n_in,
                              void* d_out, int out_size, void* d_ws, size_t ws_size,
                              hipStream_t stream) {
    const float2* mean2 = (const float2*)d_in[0];
    const float2* var2  = (const float2*)d_in[1];
    const int2*   tgt2  = (const int2*)d_in[2];
    // d_in[3] is scope (==64), baked in as SEG

    float* partial = (float*)d_ws;   // BLOCKS floats = 16 KB
    float* out = (float*)d_out;

    mledis_seg2<<<BLOCKS, TPB, 0, stream>>>(mean2, var2, tgt2, partial);
    mledis_final_reduce<<<1, TPB, 0, stream>>>(partial, out);
}